// Round 1
// baseline (787.441 us; speedup 1.0000x reference)
//
#include <hip/hip_runtime.h>

// Problem constants
#define B_        256
#define NUM_COLS_ 512
#define NUM_NODES_ 256
#define VOCAB_    100
#define D_        128
#define H_        128
#define N_        131072      // 2*B*NUM_NODES
#define E_INT_    1048576     // N*8
#define MERGED_   65536       // B*NUM_NODES
#define CAP_      48          // max in-degree tracked (Binom(1M,2^-17): P(deg>48) ~ 1e-24)
#define LN_EPS_   1e-5f
#define LDP_      136         // padded LDS row length (bf16 elems): 128+8 -> 2-way bank alias (free)

typedef __attribute__((ext_vector_type(8))) __bf16 bf16x8;
typedef __attribute__((ext_vector_type(8))) unsigned short ushort8;
typedef __attribute__((ext_vector_type(4))) float f32x4;

__device__ __forceinline__ unsigned short f2b(float f) {
  union { float f; unsigned int u; } c; c.f = f;
  unsigned int b = c.u + 0x7fffu + ((c.u >> 16) & 1u);   // RNE
  return (unsigned short)(b >> 16);
}

// ---------------- embedding gather: h[row] = emb[col, x[row]] , row = b*512+col
__global__ __launch_bounds__(256) void embed_kernel(const int* __restrict__ x,
                                                    const float* __restrict__ emb,
                                                    float* __restrict__ h) {
  int t = blockIdx.x * 256 + threadIdx.x;     // grid exactly N_*32 threads
  int row = t >> 5, q = t & 31;
  int col = row & 511;
  int tok = x[row];
  const float4* src = (const float4*)(emb + ((size_t)col * VOCAB_ + tok) * D_);
  ((float4*)h)[(size_t)row * 32 + q] = src[q];
}

// ---------------- build per-destination adjacency (cnt must be zeroed first)
__global__ __launch_bounds__(256) void scatter_kernel(const int* __restrict__ ei,
                                                      int* __restrict__ cnt,
                                                      int* __restrict__ lst) {
  int e = blockIdx.x * 256 + threadIdx.x;     // grid exactly E_INT_
  int s = ei[e], d = ei[E_INT_ + e];
  int pos = atomicAdd(&cnt[d], 1);
  if (pos < CAP_) lst[d * CAP_ + pos] = s;
}

// ---------------- edge-attr table: cTab[i][r][c] = los_table[r] @ g2_ew[i] + g2_eb[i]
__global__ void ctab_kernel(const float* __restrict__ lt, const float* __restrict__ ew,
                            const float* __restrict__ eb, float* __restrict__ cTab) {
  int blk = blockIdx.x;                       // 0..75
  int i = blk / 38, r = blk % 38, c = threadIdx.x;  // 128 threads
  float acc = eb[i * 128 + c];
  for (int k = 0; k < 8; ++k) acc += lt[r * 8 + k] * ew[(i * 8 + k) * 128 + c];
  cTab[((size_t)i * 38 + r) * 128 + c] = acc;
}

// ---------------- loop-1 aggregation: z[n] = (1+eps)*h[n] + sum_{e:dst=n} h[src[e]]
__global__ __launch_bounds__(256) void agg1_kernel(const float* __restrict__ h,
                                                   float* __restrict__ z,
                                                   const int* __restrict__ cnt,
                                                   const int* __restrict__ lst,
                                                   const float* __restrict__ eps_ptr,
                                                   int layer) {
  int wid = blockIdx.x * 4 + (threadIdx.x >> 6);   // one wave per node
  int lane = threadIdx.x & 63;
  float eps = 1.0f + eps_ptr[layer];
  int deg = cnt[wid]; deg = deg < CAP_ ? deg : CAP_;
  int sidx = (lane < deg) ? lst[wid * CAP_ + lane] : 0;
  const float2* h2 = (const float2*)h;
  float ax = 0.f, ay = 0.f;
  for (int j = 0; j < deg; ++j) {
    int s = __shfl(sidx, j);
    float2 v = h2[(size_t)s * 64 + lane];          // 512B coalesced per wave
    ax += v.x; ay += v.y;
  }
  float2 hv = h2[(size_t)wid * 64 + lane];
  float2 o; o.x = eps * hv.x + ax; o.y = eps * hv.y + ay;
  ((float2*)z)[(size_t)wid * 64 + lane] = o;
}

// ---------------- loop-2 aggregation with edge attrs + analytic extra edge
__global__ __launch_bounds__(256) void agg2_kernel(const float* __restrict__ h,
                                                   float* __restrict__ z,
                                                   const int* __restrict__ cnt,
                                                   const int* __restrict__ lst,
                                                   const float* __restrict__ cTab,
                                                   const int* __restrict__ los,
                                                   const float* __restrict__ eps_ptr,
                                                   int layer) {
  int wid = blockIdx.x * 4 + (threadIdx.x >> 6);
  int lane = threadIdx.x & 63;
  float eps = 1.0f + eps_ptr[layer];
  int deg = cnt[wid]; deg = deg < CAP_ ? deg : CAP_;
  int sidx = (lane < deg) ? lst[wid * CAP_ + lane] : 0;
  const float2* h2 = (const float2*)h;
  const float2* ct = (const float2*)(cTab + (size_t)layer * 38 * 128);
  float2 c0 = ct[lane];
  float ax = 0.f, ay = 0.f;
  for (int j = 0; j < deg; ++j) {
    int s = __shfl(sidx, j);
    float2 v = h2[(size_t)s * 64 + lane];
    ax += fmaxf(v.x + c0.x, 0.f);
    ay += fmaxf(v.y + c0.y, 0.f);
  }
  if (wid >= MERGED_) {                            // extra edge (wid-MERGED_) -> wid
    int j = wid - MERGED_;
    int lt = los[j >> 8];
    const float2* cr = (const float2*)(cTab + ((size_t)layer * 38 + lt) * 128);
    float2 cv = cr[lane];
    float2 v = h2[(size_t)j * 64 + lane];
    ax += fmaxf(v.x + cv.x, 0.f);
    ay += fmaxf(v.y + cv.y, 0.f);
  }
  float2 hv = h2[(size_t)wid * 64 + lane];
  float2 o; o.x = eps * hv.x + ax; o.y = eps * hv.y + ay;
  ((float2*)z)[(size_t)wid * 64 + lane] = o;
}

// ---------------- fused MLP: h = relu(LN(z@w1+b1)*g+be) @ w2 + b2   (bf16 MFMA)
__global__ __launch_bounds__(256, 2) void mlp_kernel(
    const float* __restrict__ zin, float* __restrict__ hout,
    const float* __restrict__ w1, const float* __restrict__ b1,
    const float* __restrict__ gg, const float* __restrict__ be,
    const float* __restrict__ w2, const float* __restrict__ b2) {
  __shared__ __align__(16) unsigned short w1t[128 * LDP_];  // w1^T bf16; reused for t
  __shared__ __align__(16) unsigned short w2t[128 * LDP_];  // w2^T bf16
  __shared__ float b1s[128], gs[128], bes[128], b2s[128];

  int tid = threadIdx.x;
  for (int it = 0; it < 64; ++it) {             // 64*256 = 128*128
    int idx = it * 256 + tid;
    int k = idx >> 7, n = idx & 127;
    w1t[n * LDP_ + k] = f2b(w1[idx]);
    w2t[n * LDP_ + k] = f2b(w2[idx]);
  }
  if (tid < 128) { b1s[tid] = b1[tid]; gs[tid] = gg[tid]; bes[tid] = be[tid]; b2s[tid] = b2[tid]; }

  int wave = tid >> 6, lane = tid & 63;
  int quad = lane >> 4, m = lane & 15;
  size_t row0 = (size_t)blockIdx.x * 128 + wave * 32;   // this wave's 32 rows

  // A-frags for GEMM1 straight from global z (A[m=lane&15][k=quad*8+j])
  bf16x8 afr[2][4];
  #pragma unroll
  for (int rb = 0; rb < 2; ++rb) {
    const float* pr = zin + (row0 + rb * 16 + m) * 128 + quad * 8;
    #pragma unroll
    for (int kc = 0; kc < 4; ++kc) {
      float4 v0 = *(const float4*)(pr + kc * 32);
      float4 v1 = *(const float4*)(pr + kc * 32 + 4);
      ushort8 u;
      u[0] = f2b(v0.x); u[1] = f2b(v0.y); u[2] = f2b(v0.z); u[3] = f2b(v0.w);
      u[4] = f2b(v1.x); u[5] = f2b(v1.y); u[6] = f2b(v1.z); u[7] = f2b(v1.w);
      afr[rb][kc] = __builtin_bit_cast(bf16x8, u);
    }
  }
  __syncthreads();   // weights staged

  f32x4 acc[2][8];
  #pragma unroll
  for (int rb = 0; rb < 2; ++rb)
    #pragma unroll
    for (int cb = 0; cb < 8; ++cb)
      acc[rb][cb] = (f32x4){0.f, 0.f, 0.f, 0.f};

  #pragma unroll
  for (int kc = 0; kc < 4; ++kc) {
    #pragma unroll
    for (int cb = 0; cb < 8; ++cb) {
      bf16x8 bfr = __builtin_bit_cast(bf16x8,
          *(const ushort8*)&w1t[(cb * 16 + m) * LDP_ + kc * 32 + quad * 8]);
      acc[0][cb] = __builtin_amdgcn_mfma_f32_16x16x32_bf16(afr[0][kc], bfr, acc[0][cb], 0, 0, 0);
      acc[1][cb] = __builtin_amdgcn_mfma_f32_16x16x32_bf16(afr[1][kc], bfr, acc[1][cb], 0, 0, 0);
    }
  }

  // bias + LayerNorm (rows live across the 16 lanes of a quad) + ReLU, in place
  #pragma unroll
  for (int rb = 0; rb < 2; ++rb) {
    #pragma unroll
    for (int reg = 0; reg < 4; ++reg) {
      float v[8]; float s1 = 0.f, s2 = 0.f;
      #pragma unroll
      for (int cb = 0; cb < 8; ++cb) {
        float xv = acc[rb][cb][reg] + b1s[cb * 16 + m];
        v[cb] = xv; s1 += xv; s2 += xv * xv;
      }
      #pragma unroll
      for (int off = 1; off < 16; off <<= 1) { s1 += __shfl_xor(s1, off); s2 += __shfl_xor(s2, off); }
      float mu  = s1 * (1.f / 128.f);
      float var = s2 * (1.f / 128.f) - mu * mu;
      float inv = rsqrtf(var + LN_EPS_);
      #pragma unroll
      for (int cb = 0; cb < 8; ++cb) {
        float xn = (v[cb] - mu) * inv * gs[cb * 16 + m] + bes[cb * 16 + m];
        acc[rb][cb][reg] = fmaxf(xn, 0.f);
      }
    }
  }

  __syncthreads();   // every wave done reading w1t -> safe to reuse for t
  int rl0 = wave * 32;
  #pragma unroll
  for (int rb = 0; rb < 2; ++rb)
    #pragma unroll
    for (int cb = 0; cb < 8; ++cb)
      #pragma unroll
      for (int reg = 0; reg < 4; ++reg)
        w1t[(rl0 + rb * 16 + quad * 4 + reg) * LDP_ + cb * 16 + m] = f2b(acc[rb][cb][reg]);
  __syncthreads();

  // GEMM2: A = t (from reused LDS), B = w2^T
  bf16x8 afr2[2][4];
  #pragma unroll
  for (int rb = 0; rb < 2; ++rb)
    #pragma unroll
    for (int kc = 0; kc < 4; ++kc)
      afr2[rb][kc] = __builtin_bit_cast(bf16x8,
          *(const ushort8*)&w1t[(rl0 + rb * 16 + m) * LDP_ + kc * 32 + quad * 8]);

  f32x4 acc2[2][8];
  #pragma unroll
  for (int rb = 0; rb < 2; ++rb)
    #pragma unroll
    for (int cb = 0; cb < 8; ++cb)
      acc2[rb][cb] = (f32x4){0.f, 0.f, 0.f, 0.f};

  #pragma unroll
  for (int kc = 0; kc < 4; ++kc) {
    #pragma unroll
    for (int cb = 0; cb < 8; ++cb) {
      bf16x8 bfr = __builtin_bit_cast(bf16x8,
          *(const ushort8*)&w2t[(cb * 16 + m) * LDP_ + kc * 32 + quad * 8]);
      acc2[0][cb] = __builtin_amdgcn_mfma_f32_16x16x32_bf16(afr2[0][kc], bfr, acc2[0][cb], 0, 0, 0);
      acc2[1][cb] = __builtin_amdgcn_mfma_f32_16x16x32_bf16(afr2[1][kc], bfr, acc2[1][cb], 0, 0, 0);
    }
  }

  #pragma unroll
  for (int rb = 0; rb < 2; ++rb)
    #pragma unroll
    for (int cb = 0; cb < 8; ++cb) {
      int col = cb * 16 + m;
      float bb = b2s[col];
      #pragma unroll
      for (int reg = 0; reg < 4; ++reg) {
        size_t r = row0 + rb * 16 + quad * 4 + reg;
        hout[r * 128 + col] = acc2[rb][cb][reg] + bb;
      }
    }
}

// ---------------- group sum: out[g, off:off+128] = sum over 256 node rows
__global__ void gsum_kernel(const float* __restrict__ h, float* __restrict__ out, int off) {
  int g = blockIdx.x, c = threadIdx.x;  // 512 blocks x 128 threads
  const float* p = h + (size_t)g * NUM_NODES_ * 128 + c;
  float acc = 0.f;
  for (int r = 0; r < NUM_NODES_; ++r) acc += p[(size_t)r * 128];
  out[(size_t)g * 256 + off + c] = acc;
}

extern "C" void kernel_launch(void* const* d_in, const int* in_sizes, int n_in,
                              void* d_out, int out_size, void* d_ws, size_t ws_size,
                              hipStream_t stream) {
  const int*   x        = (const int*)d_in[0];
  const int*   ei       = (const int*)d_in[1];
  const int*   los      = (const int*)d_in[2];
  const float* emb      = (const float*)d_in[3];
  const float* lostab   = (const float*)d_in[4];
  const float* g1_w1    = (const float*)d_in[5];
  const float* g1_b1    = (const float*)d_in[6];
  const float* g1_g     = (const float*)d_in[7];
  const float* g1_be    = (const float*)d_in[8];
  const float* g1_w2    = (const float*)d_in[9];
  const float* g1_b2    = (const float*)d_in[10];
  const float* g1_eps   = (const float*)d_in[11];
  const float* g2_w1    = (const float*)d_in[12];
  const float* g2_b1    = (const float*)d_in[13];
  const float* g2_g     = (const float*)d_in[14];
  const float* g2_be    = (const float*)d_in[15];
  const float* g2_w2    = (const float*)d_in[16];
  const float* g2_b2    = (const float*)d_in[17];
  const float* g2_eps   = (const float*)d_in[18];
  const float* g2_ew    = (const float*)d_in[19];
  const float* g2_eb    = (const float*)d_in[20];
  float* out = (float*)d_out;

  char* ws = (char*)d_ws;
  float* h   = (float*)(ws);                                   // 67,108,864 B
  float* z   = (float*)(ws + (size_t)67108864);                // 67,108,864 B
  int*   cnt = (int*)  (ws + (size_t)134217728);               // 524,288 B
  int*   lst = (int*)  (ws + (size_t)134217728 + 524288);      // N_*CAP_*4 = 25,165,824 B
  float* cTab= (float*)(ws + (size_t)134217728 + 524288 + (size_t)N_ * CAP_ * 4); // 38,912 B

  hipMemsetAsync(cnt, 0, (size_t)N_ * 4, stream);
  embed_kernel  <<<16384, 256, 0, stream>>>(x, emb, h);
  scatter_kernel<<<4096, 256, 0, stream>>>(ei, cnt, lst);
  ctab_kernel   <<<76, 128, 0, stream>>>(lostab, g2_ew, g2_eb, cTab);

  for (int i = 0; i < 2; ++i) {
    agg1_kernel<<<32768, 256, 0, stream>>>(h, z, cnt, lst, g1_eps, i);
    mlp_kernel <<<1024, 256, 0, stream>>>(z, h,
        g1_w1 + (size_t)i * 16384, g1_b1 + i * 128, g1_g + i * 128,
        g1_be + i * 128, g1_w2 + (size_t)i * 16384, g1_b2 + i * 128);
  }
  gsum_kernel<<<512, 128, 0, stream>>>(h, out, 0);

  for (int i = 0; i < 2; ++i) {
    agg2_kernel<<<32768, 256, 0, stream>>>(h, z, cnt, lst, cTab, los, g2_eps, i);
    mlp_kernel <<<1024, 256, 0, stream>>>(z, h,
        g2_w1 + (size_t)i * 16384, g2_b1 + i * 128, g2_g + i * 128,
        g2_be + i * 128, g2_w2 + (size_t)i * 16384, g2_b2 + i * 128);
  }
  gsum_kernel<<<512, 128, 0, stream>>>(h, out, 128);
}

// Round 2
// 567.423 us; speedup vs baseline: 1.3877x; 1.3877x over previous
//
#include <hip/hip_runtime.h>

// Problem constants
#define B_        256
#define NUM_COLS_ 512
#define NUM_NODES_ 256
#define VOCAB_    100
#define D_        128
#define H_        128
#define N_        131072      // 2*B*NUM_NODES
#define E_INT_    1048576     // N*8
#define MERGED_   65536       // B*NUM_NODES
#define CAP_      48          // max in-degree tracked (P(deg>48) ~ 1e-24)
#define LN_EPS_   1e-5f
#define LDP_      136         // padded LDS row (bf16 elems): 128+8 -> 2-way alias (free)

typedef __attribute__((ext_vector_type(8))) __bf16 bf16x8;
typedef __attribute__((ext_vector_type(8))) unsigned short ushort8;
typedef __attribute__((ext_vector_type(4))) float f32x4;

__device__ __forceinline__ unsigned short f2b(float f) {
  union { float f; unsigned int u; } c; c.f = f;
  unsigned int b = c.u + 0x7fffu + ((c.u >> 16) & 1u);   // RNE
  return (unsigned short)(b >> 16);
}
__device__ __forceinline__ float2 unpk(unsigned int v) {
  union { unsigned int u; float f; } a, b;
  a.u = v << 16; b.u = v & 0xffff0000u;
  return (float2){a.f, b.f};   // .x = element 2*lane, .y = element 2*lane+1
}

// ---------------- embedding gather: h_bf[row] = bf16(emb[col, x[row]]), row=b*512+col
__global__ __launch_bounds__(256) void embed_kernel(const int* __restrict__ x,
                                                    const float* __restrict__ emb,
                                                    unsigned short* __restrict__ h) {
  int t = blockIdx.x * 256 + threadIdx.x;     // grid = N_*16 threads
  int row = t >> 4, q = t & 15;
  int col = row & 511;
  int tok = x[row];
  const float4* src = (const float4*)(emb + ((size_t)col * VOCAB_ + tok) * D_) + q * 2;
  float4 v0 = src[0], v1 = src[1];
  ushort8 u;
  u[0] = f2b(v0.x); u[1] = f2b(v0.y); u[2] = f2b(v0.z); u[3] = f2b(v0.w);
  u[4] = f2b(v1.x); u[5] = f2b(v1.y); u[6] = f2b(v1.z); u[7] = f2b(v1.w);
  ((ushort8*)h)[(size_t)row * 16 + q] = u;
}

// ---------------- build per-destination adjacency (cnt zeroed first)
__global__ __launch_bounds__(256) void scatter_kernel(const int* __restrict__ ei,
                                                      int* __restrict__ cnt,
                                                      int* __restrict__ lst) {
  int e = blockIdx.x * 256 + threadIdx.x;     // grid exactly E_INT_
  int s = ei[e], d = ei[E_INT_ + e];
  int pos = atomicAdd(&cnt[d], 1);
  if (pos < CAP_) lst[d * CAP_ + pos] = s;
}

// ---------------- edge-attr table: cTab[i][r][c] = los_table[r] @ g2_ew[i] + g2_eb[i]
__global__ void ctab_kernel(const float* __restrict__ lt, const float* __restrict__ ew,
                            const float* __restrict__ eb, float* __restrict__ cTab) {
  int blk = blockIdx.x;                       // 0..75
  int i = blk / 38, r = blk % 38, c = threadIdx.x;  // 128 threads
  float acc = eb[i * 128 + c];
  for (int k = 0; k < 8; ++k) acc += lt[r * 8 + k] * ew[(i * 8 + k) * 128 + c];
  cTab[((size_t)i * 38 + r) * 128 + c] = acc;
}

// ---------------- loop-1 aggregation (bf16 in/out, fp32 accumulate), 4x unrolled gather
__global__ __launch_bounds__(256) void agg1_kernel(const unsigned short* __restrict__ h,
                                                   unsigned short* __restrict__ z,
                                                   const int* __restrict__ cnt,
                                                   const int* __restrict__ lst,
                                                   const float* __restrict__ eps_ptr,
                                                   int layer) {
  int wid = blockIdx.x * 4 + (threadIdx.x >> 6);   // one wave per node
  int lane = threadIdx.x & 63;
  float eps = 1.0f + eps_ptr[layer];
  int deg = cnt[wid]; deg = deg < CAP_ ? deg : CAP_;
  int sidx = (lane < deg) ? lst[wid * CAP_ + lane] : 0;
  const unsigned int* hb = (const unsigned int*)h;
  float ax = 0.f, ay = 0.f;
  int it = (deg + 3) >> 2;
  for (int t = 0; t < it; ++t) {
    int j = t << 2;
    int s0 = __shfl(sidx, j),     s1 = __shfl(sidx, j | 1);
    int s2 = __shfl(sidx, j | 2), s3 = __shfl(sidx, j | 3);
    unsigned int v0 = hb[(size_t)s0 * 64 + lane];
    unsigned int v1 = hb[(size_t)s1 * 64 + lane];
    unsigned int v2 = hb[(size_t)s2 * 64 + lane];
    unsigned int v3 = hb[(size_t)s3 * 64 + lane];
    float w1 = (j + 1 < deg) ? 1.f : 0.f;
    float w2 = (j + 2 < deg) ? 1.f : 0.f;
    float w3 = (j + 3 < deg) ? 1.f : 0.f;
    float2 f0 = unpk(v0), f1 = unpk(v1), f2 = unpk(v2), f3 = unpk(v3);
    ax += f0.x + w1 * f1.x + w2 * f2.x + w3 * f3.x;
    ay += f0.y + w1 * f1.y + w2 * f2.y + w3 * f3.y;
  }
  float2 hv = unpk(hb[(size_t)wid * 64 + lane]);
  float ox = eps * hv.x + ax, oy = eps * hv.y + ay;
  unsigned int o = ((unsigned int)f2b(oy) << 16) | f2b(ox);
  ((unsigned int*)z)[(size_t)wid * 64 + lane] = o;
}

// ---------------- loop-2 aggregation with edge attrs + analytic extra edge
__global__ __launch_bounds__(256) void agg2_kernel(const unsigned short* __restrict__ h,
                                                   unsigned short* __restrict__ z,
                                                   const int* __restrict__ cnt,
                                                   const int* __restrict__ lst,
                                                   const float* __restrict__ cTab,
                                                   const int* __restrict__ los,
                                                   const float* __restrict__ eps_ptr,
                                                   int layer) {
  int wid = blockIdx.x * 4 + (threadIdx.x >> 6);
  int lane = threadIdx.x & 63;
  float eps = 1.0f + eps_ptr[layer];
  int deg = cnt[wid]; deg = deg < CAP_ ? deg : CAP_;
  int sidx = (lane < deg) ? lst[wid * CAP_ + lane] : 0;
  const unsigned int* hb = (const unsigned int*)h;
  const float2* ct = (const float2*)(cTab + (size_t)layer * 38 * 128);
  float2 c0 = ct[lane];
  float ax = 0.f, ay = 0.f;
  int it = (deg + 3) >> 2;
  for (int t = 0; t < it; ++t) {
    int j = t << 2;
    int s0 = __shfl(sidx, j),     s1 = __shfl(sidx, j | 1);
    int s2 = __shfl(sidx, j | 2), s3 = __shfl(sidx, j | 3);
    unsigned int v0 = hb[(size_t)s0 * 64 + lane];
    unsigned int v1 = hb[(size_t)s1 * 64 + lane];
    unsigned int v2 = hb[(size_t)s2 * 64 + lane];
    unsigned int v3 = hb[(size_t)s3 * 64 + lane];
    float w1 = (j + 1 < deg) ? 1.f : 0.f;
    float w2 = (j + 2 < deg) ? 1.f : 0.f;
    float w3 = (j + 3 < deg) ? 1.f : 0.f;
    float2 f0 = unpk(v0), f1 = unpk(v1), f2 = unpk(v2), f3 = unpk(v3);
    ax += fmaxf(f0.x + c0.x, 0.f) + w1 * fmaxf(f1.x + c0.x, 0.f)
        + w2 * fmaxf(f2.x + c0.x, 0.f) + w3 * fmaxf(f3.x + c0.x, 0.f);
    ay += fmaxf(f0.y + c0.y, 0.f) + w1 * fmaxf(f1.y + c0.y, 0.f)
        + w2 * fmaxf(f2.y + c0.y, 0.f) + w3 * fmaxf(f3.y + c0.y, 0.f);
  }
  if (wid >= MERGED_) {                            // extra edge (wid-MERGED_) -> wid
    int j = wid - MERGED_;
    int lt = los[j >> 8];
    const float2* cr = (const float2*)(cTab + ((size_t)layer * 38 + lt) * 128);
    float2 cv = cr[lane];
    float2 v = unpk(hb[(size_t)j * 64 + lane]);
    ax += fmaxf(v.x + cv.x, 0.f);
    ay += fmaxf(v.y + cv.y, 0.f);
  }
  float2 hv = unpk(hb[(size_t)wid * 64 + lane]);
  float ox = eps * hv.x + ax, oy = eps * hv.y + ay;
  unsigned int o = ((unsigned int)f2b(oy) << 16) | f2b(ox);
  ((unsigned int*)z)[(size_t)wid * 64 + lane] = o;
}

// ---------------- fused MLP: h = relu(LN(z@w1+b1)*g+be) @ w2 + b2   (bf16 MFMA)
__global__ __launch_bounds__(256, 2) void mlp_kernel(
    const unsigned short* __restrict__ zin, unsigned short* __restrict__ hout,
    const float* __restrict__ w1, const float* __restrict__ b1,
    const float* __restrict__ gg, const float* __restrict__ be,
    const float* __restrict__ w2, const float* __restrict__ b2) {
  __shared__ __align__(16) unsigned short w1t[128 * LDP_];  // w1^T bf16; reused for t
  __shared__ __align__(16) unsigned short w2t[128 * LDP_];  // w2^T bf16
  __shared__ float b1s[128], gs[128], bes[128], b2s[128];

  int tid = threadIdx.x;
  for (int it = 0; it < 64; ++it) {             // 64*256 = 128*128
    int idx = it * 256 + tid;
    int k = idx >> 7, n = idx & 127;
    w1t[n * LDP_ + k] = f2b(w1[idx]);
    w2t[n * LDP_ + k] = f2b(w2[idx]);
  }
  if (tid < 128) { b1s[tid] = b1[tid]; gs[tid] = gg[tid]; bes[tid] = be[tid]; b2s[tid] = b2[tid]; }

  int wave = tid >> 6, lane = tid & 63;
  int quad = lane >> 4, m = lane & 15;
  size_t row0 = (size_t)blockIdx.x * 128 + wave * 32;   // this wave's 32 rows

  // A-frags for GEMM1 straight from global bf16 z (A[m=lane&15][k=quad*8+j])
  bf16x8 afr[2][4];
  #pragma unroll
  for (int rb = 0; rb < 2; ++rb) {
    const unsigned short* pr = zin + (row0 + rb * 16 + m) * 128 + quad * 8;
    #pragma unroll
    for (int kc = 0; kc < 4; ++kc)
      afr[rb][kc] = __builtin_bit_cast(bf16x8, *(const ushort8*)(pr + kc * 32));
  }
  __syncthreads();   // weights staged

  f32x4 acc[2][8];
  #pragma unroll
  for (int rb = 0; rb < 2; ++rb)
    #pragma unroll
    for (int cb = 0; cb < 8; ++cb)
      acc[rb][cb] = (f32x4){0.f, 0.f, 0.f, 0.f};

  #pragma unroll
  for (int kc = 0; kc < 4; ++kc) {
    #pragma unroll
    for (int cb = 0; cb < 8; ++cb) {
      bf16x8 bfr = __builtin_bit_cast(bf16x8,
          *(const ushort8*)&w1t[(cb * 16 + m) * LDP_ + kc * 32 + quad * 8]);
      acc[0][cb] = __builtin_amdgcn_mfma_f32_16x16x32_bf16(afr[0][kc], bfr, acc[0][cb], 0, 0, 0);
      acc[1][cb] = __builtin_amdgcn_mfma_f32_16x16x32_bf16(afr[1][kc], bfr, acc[1][cb], 0, 0, 0);
    }
  }

  // bias + LayerNorm (row spread over 16 lanes of a quad, 8 cb) + ReLU, in place
  #pragma unroll
  for (int rb = 0; rb < 2; ++rb) {
    #pragma unroll
    for (int reg = 0; reg < 4; ++reg) {
      float v[8]; float s1 = 0.f, s2 = 0.f;
      #pragma unroll
      for (int cb = 0; cb < 8; ++cb) {
        float xv = acc[rb][cb][reg] + b1s[cb * 16 + m];
        v[cb] = xv; s1 += xv; s2 += xv * xv;
      }
      #pragma unroll
      for (int off = 1; off < 16; off <<= 1) { s1 += __shfl_xor(s1, off); s2 += __shfl_xor(s2, off); }
      float mu  = s1 * (1.f / 128.f);
      float var = s2 * (1.f / 128.f) - mu * mu;
      float inv = rsqrtf(var + LN_EPS_);
      #pragma unroll
      for (int cb = 0; cb < 8; ++cb) {
        float xn = (v[cb] - mu) * inv * gs[cb * 16 + m] + bes[cb * 16 + m];
        acc[rb][cb][reg] = fmaxf(xn, 0.f);
      }
    }
  }

  __syncthreads();   // every wave done reading w1t -> safe to reuse for t
  int rl0 = wave * 32;
  #pragma unroll
  for (int rb = 0; rb < 2; ++rb)
    #pragma unroll
    for (int cb = 0; cb < 8; ++cb)
      #pragma unroll
      for (int reg = 0; reg < 4; ++reg)
        w1t[(rl0 + rb * 16 + quad * 4 + reg) * LDP_ + cb * 16 + m] = f2b(acc[rb][cb][reg]);
  __syncthreads();

  // GEMM2: A = t (reused LDS), B = w2^T
  bf16x8 afr2[2][4];
  #pragma unroll
  for (int rb = 0; rb < 2; ++rb)
    #pragma unroll
    for (int kc = 0; kc < 4; ++kc)
      afr2[rb][kc] = __builtin_bit_cast(bf16x8,
          *(const ushort8*)&w1t[(rl0 + rb * 16 + m) * LDP_ + kc * 32 + quad * 8]);

  f32x4 acc2[2][8];
  #pragma unroll
  for (int rb = 0; rb < 2; ++rb)
    #pragma unroll
    for (int cb = 0; cb < 8; ++cb)
      acc2[rb][cb] = (f32x4){0.f, 0.f, 0.f, 0.f};

  #pragma unroll
  for (int kc = 0; kc < 4; ++kc) {
    #pragma unroll
    for (int cb = 0; cb < 8; ++cb) {
      bf16x8 bfr = __builtin_bit_cast(bf16x8,
          *(const ushort8*)&w2t[(cb * 16 + m) * LDP_ + kc * 32 + quad * 8]);
      acc2[0][cb] = __builtin_amdgcn_mfma_f32_16x16x32_bf16(afr2[0][kc], bfr, acc2[0][cb], 0, 0, 0);
      acc2[1][cb] = __builtin_amdgcn_mfma_f32_16x16x32_bf16(afr2[1][kc], bfr, acc2[1][cb], 0, 0, 0);
    }
  }

  #pragma unroll
  for (int rb = 0; rb < 2; ++rb)
    #pragma unroll
    for (int cb = 0; cb < 8; ++cb) {
      int col = cb * 16 + m;
      float bb = b2s[col];
      #pragma unroll
      for (int reg = 0; reg < 4; ++reg) {
        size_t r = row0 + rb * 16 + quad * 4 + reg;
        hout[r * 128 + col] = f2b(acc2[rb][cb][reg] + bb);
      }
    }
}

// ---------------- group sum (bf16 in, fp32 out): out[g, off:off+128] = sum 256 rows
__global__ void gsum_kernel(const unsigned short* __restrict__ h, float* __restrict__ out, int off) {
  int g = blockIdx.x, c = threadIdx.x;  // 512 blocks x 128 threads
  const unsigned short* p = h + (size_t)g * NUM_NODES_ * 128 + c;
  float acc = 0.f;
  for (int r = 0; r < NUM_NODES_; ++r) {
    union { unsigned int u; float f; } cv;
    cv.u = ((unsigned int)p[(size_t)r * 128]) << 16;
    acc += cv.f;
  }
  out[(size_t)g * 256 + off + c] = acc;
}

extern "C" void kernel_launch(void* const* d_in, const int* in_sizes, int n_in,
                              void* d_out, int out_size, void* d_ws, size_t ws_size,
                              hipStream_t stream) {
  const int*   x        = (const int*)d_in[0];
  const int*   ei       = (const int*)d_in[1];
  const int*   los      = (const int*)d_in[2];
  const float* emb      = (const float*)d_in[3];
  const float* lostab   = (const float*)d_in[4];
  const float* g1_w1    = (const float*)d_in[5];
  const float* g1_b1    = (const float*)d_in[6];
  const float* g1_g     = (const float*)d_in[7];
  const float* g1_be    = (const float*)d_in[8];
  const float* g1_w2    = (const float*)d_in[9];
  const float* g1_b2    = (const float*)d_in[10];
  const float* g1_eps   = (const float*)d_in[11];
  const float* g2_w1    = (const float*)d_in[12];
  const float* g2_b1    = (const float*)d_in[13];
  const float* g2_g     = (const float*)d_in[14];
  const float* g2_be    = (const float*)d_in[15];
  const float* g2_w2    = (const float*)d_in[16];
  const float* g2_b2    = (const float*)d_in[17];
  const float* g2_eps   = (const float*)d_in[18];
  const float* g2_ew    = (const float*)d_in[19];
  const float* g2_eb    = (const float*)d_in[20];
  float* out = (float*)d_out;

  char* ws = (char*)d_ws;
  unsigned short* h = (unsigned short*)(ws);                        // 33,554,432 B
  unsigned short* z = (unsigned short*)(ws + (size_t)33554432);     // 33,554,432 B
  int*   cnt = (int*)  (ws + (size_t)67108864);                     // 524,288 B
  int*   lst = (int*)  (ws + (size_t)67108864 + 524288);            // 25,165,824 B
  float* cTab= (float*)(ws + (size_t)67108864 + 524288 + (size_t)N_ * CAP_ * 4);

  hipMemsetAsync(cnt, 0, (size_t)N_ * 4, stream);
  embed_kernel  <<<8192, 256, 0, stream>>>(x, emb, h);
  scatter_kernel<<<4096, 256, 0, stream>>>(ei, cnt, lst);
  ctab_kernel   <<<76, 128, 0, stream>>>(lostab, g2_ew, g2_eb, cTab);

  for (int i = 0; i < 2; ++i) {
    agg1_kernel<<<32768, 256, 0, stream>>>(h, z, cnt, lst, g1_eps, i);
    mlp_kernel <<<1024, 256, 0, stream>>>(z, h,
        g1_w1 + (size_t)i * 16384, g1_b1 + i * 128, g1_g + i * 128,
        g1_be + i * 128, g1_w2 + (size_t)i * 16384, g1_b2 + i * 128);
  }
  gsum_kernel<<<512, 128, 0, stream>>>(h, out, 0);

  for (int i = 0; i < 2; ++i) {
    agg2_kernel<<<32768, 256, 0, stream>>>(h, z, cnt, lst, cTab, los, g2_eps, i);
    mlp_kernel <<<1024, 256, 0, stream>>>(z, h,
        g2_w1 + (size_t)i * 16384, g2_b1 + i * 128, g2_g + i * 128,
        g2_be + i * 128, g2_w2 + (size_t)i * 16384, g2_b2 + i * 128);
  }
  gsum_kernel<<<512, 128, 0, stream>>>(h, out, 128);
}

// Round 3
// 552.844 us; speedup vs baseline: 1.4243x; 1.0264x over previous
//
#include <hip/hip_runtime.h>

// Problem constants
#define B_        256
#define NUM_COLS_ 512
#define NUM_NODES_ 256
#define VOCAB_    100
#define D_        128
#define H_        128
#define N_        131072      // 2*B*NUM_NODES
#define E_INT_    1048576     // N*8
#define MERGED_   65536       // B*NUM_NODES
#define LN_EPS_   1e-5f
#define LDP_      136         // padded LDS row (bf16 elems): 128+8; 272B row = 17*16B (16B-aligned)

typedef __attribute__((ext_vector_type(8))) __bf16 bf16x8;
typedef __attribute__((ext_vector_type(8))) unsigned short ushort8;
typedef __attribute__((ext_vector_type(4))) float f32x4;

__device__ __forceinline__ unsigned short f2b(float f) {
  union { float f; unsigned int u; } c; c.f = f;
  unsigned int b = c.u + 0x7fffu + ((c.u >> 16) & 1u);   // RNE
  return (unsigned short)(b >> 16);
}
__device__ __forceinline__ float2 unpk(unsigned int v) {
  union { unsigned int u; float f; } a, b;
  a.u = v << 16; b.u = v & 0xffff0000u;
  return (float2){a.f, b.f};   // .x = elem 2*lane, .y = elem 2*lane+1
}

// ---------------- embedding gather
__global__ __launch_bounds__(256) void embed_kernel(const int* __restrict__ x,
                                                    const float* __restrict__ emb,
                                                    unsigned short* __restrict__ h) {
  int t = blockIdx.x * 256 + threadIdx.x;     // grid = N_*16 threads
  int row = t >> 4, q = t & 15;
  int col = row & 511;
  int tok = x[row];
  const float4* src = (const float4*)(emb + ((size_t)col * VOCAB_ + tok) * D_) + q * 2;
  float4 v0 = src[0], v1 = src[1];
  ushort8 u;
  u[0] = f2b(v0.x); u[1] = f2b(v0.y); u[2] = f2b(v0.z); u[3] = f2b(v0.w);
  u[4] = f2b(v1.x); u[5] = f2b(v1.y); u[6] = f2b(v1.z); u[7] = f2b(v1.w);
  ((ushort8*)h)[(size_t)row * 16 + q] = u;
}

// ---------------- CSR build: count -> scan(2-level) -> fill
__global__ __launch_bounds__(256) void count_kernel(const int* __restrict__ ei,
                                                    int* __restrict__ cnt) {
  int e = blockIdx.x * 256 + threadIdx.x;
  atomicAdd(&cnt[ei[E_INT_ + e]], 1);
}

__global__ __launch_bounds__(256) void scanA_kernel(const int* __restrict__ cnt,
                                                    int* __restrict__ bsum) {
  __shared__ int sc[256];
  int tid = threadIdx.x;
  sc[tid] = cnt[blockIdx.x * 256 + tid];
  __syncthreads();
  for (int off = 128; off > 0; off >>= 1) {
    if (tid < off) sc[tid] += sc[tid + off];
    __syncthreads();
  }
  if (tid == 0) bsum[blockIdx.x] = sc[0];
}

__global__ __launch_bounds__(512) void scanB_kernel(int* __restrict__ bsum) {
  __shared__ int sb[512];
  int tid = threadIdx.x;
  int v = bsum[tid];
  sb[tid] = v;
  __syncthreads();
  for (int off = 1; off < 512; off <<= 1) {
    int a = (tid >= off) ? sb[tid - off] : 0;
    __syncthreads();
    sb[tid] += a;
    __syncthreads();
  }
  bsum[tid] = sb[tid] - v;   // exclusive
}

__global__ __launch_bounds__(256) void scanC_kernel(const int* __restrict__ cnt,
                                                    const int* __restrict__ bsum,
                                                    int* __restrict__ start,
                                                    int* __restrict__ cur) {
  __shared__ int sc[256];
  int tid = threadIdx.x;
  int t = blockIdx.x * 256 + tid;
  int v = cnt[t];
  sc[tid] = v;
  __syncthreads();
  for (int off = 1; off < 256; off <<= 1) {
    int a = (tid >= off) ? sc[tid - off] : 0;
    __syncthreads();
    sc[tid] += a;
    __syncthreads();
  }
  int st = bsum[blockIdx.x] + sc[tid] - v;   // global exclusive prefix
  start[t] = st;
  cur[t] = st;
}

__global__ __launch_bounds__(256) void fill_kernel(const int* __restrict__ ei,
                                                   int* __restrict__ cur,
                                                   int* __restrict__ lst) {
  int e = blockIdx.x * 256 + threadIdx.x;
  int s = ei[e], d = ei[E_INT_ + e];
  int pos = atomicAdd(&cur[d], 1);
  lst[pos] = s;
}

// ---------------- edge-attr table
__global__ void ctab_kernel(const float* __restrict__ lt, const float* __restrict__ ew,
                            const float* __restrict__ eb, float* __restrict__ cTab) {
  int blk = blockIdx.x;                       // 0..75
  int i = blk / 38, r = blk % 38, c = threadIdx.x;
  float acc = eb[i * 128 + c];
  for (int k = 0; k < 8; ++k) acc += lt[r * 8 + k] * ew[(i * 8 + k) * 128 + c];
  cTab[((size_t)i * 38 + r) * 128 + c] = acc;
}

// ---------------- weight pre-transpose+convert: wT[mi][n*128+k] = bf16(w[k*128+n])
__global__ __launch_bounds__(256) void wtrans_kernel(const float* __restrict__ a,
                                                     const float* __restrict__ b,
                                                     const float* __restrict__ c,
                                                     const float* __restrict__ d,
                                                     unsigned short* __restrict__ wT) {
  int o = blockIdx.x * 256 + threadIdx.x;     // grid 512*256 = 8*16384
  int mi = o >> 14;
  const float* srcs[4] = {a, b, c, d};
  const float* p = srcs[mi >> 1] + (mi & 1) * 16384;
  int j = o & 16383, n = j >> 7, k = j & 127;
  wT[o] = f2b(p[k * 128 + n]);
}

// ---------------- loop-1 aggregation: 2 nodes/wave, 8 outstanding gathers
__global__ __launch_bounds__(256) void agg1_kernel(const unsigned short* __restrict__ h,
                                                   unsigned short* __restrict__ z,
                                                   const int* __restrict__ start,
                                                   const int* __restrict__ cnt,
                                                   const int* __restrict__ lst,
                                                   const float* __restrict__ eps_ptr,
                                                   int layer) {
  int wv = blockIdx.x * 4 + (threadIdx.x >> 6);   // wave id; grid 16384 blocks
  int lane = threadIdx.x & 63;
  int wid0 = wv * 2, wid1 = wid0 + 1;
  float eps = 1.0f + eps_ptr[layer];
  int d0 = cnt[wid0]; d0 = d0 < 64 ? d0 : 64;
  int d1 = cnt[wid1]; d1 = d1 < 64 ? d1 : 64;
  int b0 = start[wid0], b1 = start[wid1];
  int i0 = (lane < d0) ? lst[b0 + lane] : 0;
  int i1 = (lane < d1) ? lst[b1 + lane] : 0;
  const unsigned int* hb = (const unsigned int*)h;
  float ax0 = 0.f, ay0 = 0.f, ax1 = 0.f, ay1 = 0.f;
  int it0 = (d0 + 3) >> 2, it1 = (d1 + 3) >> 2;
  int itm = it0 > it1 ? it0 : it1;
  for (int t = 0; t < itm; ++t) {
    int j = t << 2;
    unsigned int v00 = 0, v01 = 0, v02 = 0, v03 = 0;
    unsigned int v10 = 0, v11 = 0, v12 = 0, v13 = 0;
    if (t < it0) {
      int a = __shfl(i0, j), b = __shfl(i0, j | 1), c = __shfl(i0, j | 2), d = __shfl(i0, j | 3);
      v00 = hb[(size_t)a * 64 + lane]; v01 = hb[(size_t)b * 64 + lane];
      v02 = hb[(size_t)c * 64 + lane]; v03 = hb[(size_t)d * 64 + lane];
    }
    if (t < it1) {
      int a = __shfl(i1, j), b = __shfl(i1, j | 1), c = __shfl(i1, j | 2), d = __shfl(i1, j | 3);
      v10 = hb[(size_t)a * 64 + lane]; v11 = hb[(size_t)b * 64 + lane];
      v12 = hb[(size_t)c * 64 + lane]; v13 = hb[(size_t)d * 64 + lane];
    }
    if (t < it0) {
      float w1 = (j + 1 < d0) ? 1.f : 0.f, w2 = (j + 2 < d0) ? 1.f : 0.f, w3 = (j + 3 < d0) ? 1.f : 0.f;
      float2 f0 = unpk(v00), f1 = unpk(v01), f2 = unpk(v02), f3 = unpk(v03);
      ax0 += f0.x + w1 * f1.x + w2 * f2.x + w3 * f3.x;
      ay0 += f0.y + w1 * f1.y + w2 * f2.y + w3 * f3.y;
    }
    if (t < it1) {
      float w1 = (j + 1 < d1) ? 1.f : 0.f, w2 = (j + 2 < d1) ? 1.f : 0.f, w3 = (j + 3 < d1) ? 1.f : 0.f;
      float2 f0 = unpk(v10), f1 = unpk(v11), f2 = unpk(v12), f3 = unpk(v13);
      ax1 += f0.x + w1 * f1.x + w2 * f2.x + w3 * f3.x;
      ay1 += f0.y + w1 * f1.y + w2 * f2.y + w3 * f3.y;
    }
  }
  float2 h0 = unpk(hb[(size_t)wid0 * 64 + lane]);
  float2 h1 = unpk(hb[(size_t)wid1 * 64 + lane]);
  unsigned int* zb = (unsigned int*)z;
  float ox0 = eps * h0.x + ax0, oy0 = eps * h0.y + ay0;
  float ox1 = eps * h1.x + ax1, oy1 = eps * h1.y + ay1;
  zb[(size_t)wid0 * 64 + lane] = ((unsigned int)f2b(oy0) << 16) | f2b(ox0);
  zb[(size_t)wid1 * 64 + lane] = ((unsigned int)f2b(oy1) << 16) | f2b(ox1);
}

// ---------------- loop-2 aggregation with edge attrs + analytic extra edge
__global__ __launch_bounds__(256) void agg2_kernel(const unsigned short* __restrict__ h,
                                                   unsigned short* __restrict__ z,
                                                   const int* __restrict__ start,
                                                   const int* __restrict__ cnt,
                                                   const int* __restrict__ lst,
                                                   const float* __restrict__ cTab,
                                                   const int* __restrict__ los,
                                                   const float* __restrict__ eps_ptr,
                                                   int layer) {
  int wv = blockIdx.x * 4 + (threadIdx.x >> 6);
  int lane = threadIdx.x & 63;
  int wid0 = wv * 2, wid1 = wid0 + 1;
  float eps = 1.0f + eps_ptr[layer];
  int d0 = cnt[wid0]; d0 = d0 < 64 ? d0 : 64;
  int d1 = cnt[wid1]; d1 = d1 < 64 ? d1 : 64;
  int b0 = start[wid0], b1 = start[wid1];
  int i0 = (lane < d0) ? lst[b0 + lane] : 0;
  int i1 = (lane < d1) ? lst[b1 + lane] : 0;
  const unsigned int* hb = (const unsigned int*)h;
  const float2* ct = (const float2*)(cTab + (size_t)layer * 38 * 128);
  float2 c0 = ct[lane];
  float ax0 = 0.f, ay0 = 0.f, ax1 = 0.f, ay1 = 0.f;
  int it0 = (d0 + 3) >> 2, it1 = (d1 + 3) >> 2;
  int itm = it0 > it1 ? it0 : it1;
  for (int t = 0; t < itm; ++t) {
    int j = t << 2;
    unsigned int v00 = 0, v01 = 0, v02 = 0, v03 = 0;
    unsigned int v10 = 0, v11 = 0, v12 = 0, v13 = 0;
    if (t < it0) {
      int a = __shfl(i0, j), b = __shfl(i0, j | 1), c = __shfl(i0, j | 2), d = __shfl(i0, j | 3);
      v00 = hb[(size_t)a * 64 + lane]; v01 = hb[(size_t)b * 64 + lane];
      v02 = hb[(size_t)c * 64 + lane]; v03 = hb[(size_t)d * 64 + lane];
    }
    if (t < it1) {
      int a = __shfl(i1, j), b = __shfl(i1, j | 1), c = __shfl(i1, j | 2), d = __shfl(i1, j | 3);
      v10 = hb[(size_t)a * 64 + lane]; v11 = hb[(size_t)b * 64 + lane];
      v12 = hb[(size_t)c * 64 + lane]; v13 = hb[(size_t)d * 64 + lane];
    }
    if (t < it0) {
      float w1 = (j + 1 < d0) ? 1.f : 0.f, w2 = (j + 2 < d0) ? 1.f : 0.f, w3 = (j + 3 < d0) ? 1.f : 0.f;
      float2 f0 = unpk(v00), f1 = unpk(v01), f2 = unpk(v02), f3 = unpk(v03);
      ax0 += fmaxf(f0.x + c0.x, 0.f) + w1 * fmaxf(f1.x + c0.x, 0.f)
           + w2 * fmaxf(f2.x + c0.x, 0.f) + w3 * fmaxf(f3.x + c0.x, 0.f);
      ay0 += fmaxf(f0.y + c0.y, 0.f) + w1 * fmaxf(f1.y + c0.y, 0.f)
           + w2 * fmaxf(f2.y + c0.y, 0.f) + w3 * fmaxf(f3.y + c0.y, 0.f);
    }
    if (t < it1) {
      float w1 = (j + 1 < d1) ? 1.f : 0.f, w2 = (j + 2 < d1) ? 1.f : 0.f, w3 = (j + 3 < d1) ? 1.f : 0.f;
      float2 f0 = unpk(v10), f1 = unpk(v11), f2 = unpk(v12), f3 = unpk(v13);
      ax1 += fmaxf(f0.x + c0.x, 0.f) + w1 * fmaxf(f1.x + c0.x, 0.f)
           + w2 * fmaxf(f2.x + c0.x, 0.f) + w3 * fmaxf(f3.x + c0.x, 0.f);
      ay1 += fmaxf(f0.y + c0.y, 0.f) + w1 * fmaxf(f1.y + c0.y, 0.f)
           + w2 * fmaxf(f2.y + c0.y, 0.f) + w3 * fmaxf(f3.y + c0.y, 0.f);
    }
  }
  if (wid0 >= MERGED_) {      // both nodes get an extra edge (j -> j+MERGED_)
    int j0 = wid0 - MERGED_, j1 = wid1 - MERGED_;
    int lt0 = los[j0 >> 8], lt1 = los[j1 >> 8];
    const float2* cr0 = (const float2*)(cTab + ((size_t)layer * 38 + lt0) * 128);
    const float2* cr1 = (const float2*)(cTab + ((size_t)layer * 38 + lt1) * 128);
    float2 cv0 = cr0[lane], cv1 = cr1[lane];
    float2 v0 = unpk(hb[(size_t)j0 * 64 + lane]);
    float2 v1 = unpk(hb[(size_t)j1 * 64 + lane]);
    ax0 += fmaxf(v0.x + cv0.x, 0.f); ay0 += fmaxf(v0.y + cv0.y, 0.f);
    ax1 += fmaxf(v1.x + cv1.x, 0.f); ay1 += fmaxf(v1.y + cv1.y, 0.f);
  }
  float2 h0 = unpk(hb[(size_t)wid0 * 64 + lane]);
  float2 h1 = unpk(hb[(size_t)wid1 * 64 + lane]);
  unsigned int* zb = (unsigned int*)z;
  float ox0 = eps * h0.x + ax0, oy0 = eps * h0.y + ay0;
  float ox1 = eps * h1.x + ax1, oy1 = eps * h1.y + ay1;
  zb[(size_t)wid0 * 64 + lane] = ((unsigned int)f2b(oy0) << 16) | f2b(ox0);
  zb[(size_t)wid1 * 64 + lane] = ((unsigned int)f2b(oy1) << 16) | f2b(ox1);
}

// ---------------- fused MLP (+ optional fused group-sum epilogue)
// mode bit0: write h; bit1: atomicAdd per-group column sums into osum
__global__ __launch_bounds__(256, 2) void mlp_kernel(
    const unsigned short* __restrict__ zin, unsigned short* __restrict__ hout,
    const unsigned short* __restrict__ w1g, const unsigned short* __restrict__ w2g,
    const float* __restrict__ b1, const float* __restrict__ gg,
    const float* __restrict__ be, const float* __restrict__ b2,
    float* __restrict__ osum, int mode) {
  __shared__ __align__(16) unsigned short w1t[128 * LDP_];  // w1^T bf16; reused for t
  __shared__ __align__(16) unsigned short w2t[128 * LDP_];  // w2^T bf16
  __shared__ float b1s[128], gs[128], bes[128], b2s[128], sred[128];

  int tid = threadIdx.x;
  #pragma unroll
  for (int it = 0; it < 8; ++it) {            // 8*256*8 = 16384 bf16 per matrix
    int flat = it * 2048 + tid * 8;
    int n = flat >> 7, k = flat & 127;
    *(ushort8*)&w1t[n * LDP_ + k] = *(const ushort8*)(w1g + flat);
    *(ushort8*)&w2t[n * LDP_ + k] = *(const ushort8*)(w2g + flat);
  }
  if (tid < 128) {
    b1s[tid] = b1[tid]; gs[tid] = gg[tid]; bes[tid] = be[tid]; b2s[tid] = b2[tid];
    sred[tid] = 0.f;
  }

  int wave = tid >> 6, lane = tid & 63;
  int quad = lane >> 4, m = lane & 15;
  size_t row0 = (size_t)blockIdx.x * 128 + wave * 32;

  // A-frags for GEMM1 from global bf16 z
  bf16x8 afr[2][4];
  #pragma unroll
  for (int rb = 0; rb < 2; ++rb) {
    const unsigned short* pr = zin + (row0 + rb * 16 + m) * 128 + quad * 8;
    #pragma unroll
    for (int kc = 0; kc < 4; ++kc)
      afr[rb][kc] = __builtin_bit_cast(bf16x8, *(const ushort8*)(pr + kc * 32));
  }
  __syncthreads();

  f32x4 acc[2][8];
  #pragma unroll
  for (int rb = 0; rb < 2; ++rb)
    #pragma unroll
    for (int cb = 0; cb < 8; ++cb)
      acc[rb][cb] = (f32x4){0.f, 0.f, 0.f, 0.f};

  #pragma unroll
  for (int kc = 0; kc < 4; ++kc) {
    #pragma unroll
    for (int cb = 0; cb < 8; ++cb) {
      bf16x8 bfr = __builtin_bit_cast(bf16x8,
          *(const ushort8*)&w1t[(cb * 16 + m) * LDP_ + kc * 32 + quad * 8]);
      acc[0][cb] = __builtin_amdgcn_mfma_f32_16x16x32_bf16(afr[0][kc], bfr, acc[0][cb], 0, 0, 0);
      acc[1][cb] = __builtin_amdgcn_mfma_f32_16x16x32_bf16(afr[1][kc], bfr, acc[1][cb], 0, 0, 0);
    }
  }

  // bias + LN + ReLU
  #pragma unroll
  for (int rb = 0; rb < 2; ++rb) {
    #pragma unroll
    for (int reg = 0; reg < 4; ++reg) {
      float v[8]; float s1 = 0.f, s2 = 0.f;
      #pragma unroll
      for (int cb = 0; cb < 8; ++cb) {
        float xv = acc[rb][cb][reg] + b1s[cb * 16 + m];
        v[cb] = xv; s1 += xv; s2 += xv * xv;
      }
      #pragma unroll
      for (int off = 1; off < 16; off <<= 1) { s1 += __shfl_xor(s1, off); s2 += __shfl_xor(s2, off); }
      float mu  = s1 * (1.f / 128.f);
      float var = s2 * (1.f / 128.f) - mu * mu;
      float inv = rsqrtf(var + LN_EPS_);
      #pragma unroll
      for (int cb = 0; cb < 8; ++cb) {
        float xn = (v[cb] - mu) * inv * gs[cb * 16 + m] + bes[cb * 16 + m];
        acc[rb][cb][reg] = fmaxf(xn, 0.f);
      }
    }
  }

  __syncthreads();   // all waves done with w1t -> reuse for t
  int rl0 = wave * 32;
  #pragma unroll
  for (int rb = 0; rb < 2; ++rb)
    #pragma unroll
    for (int cb = 0; cb < 8; ++cb)
      #pragma unroll
      for (int reg = 0; reg < 4; ++reg)
        w1t[(rl0 + rb * 16 + quad * 4 + reg) * LDP_ + cb * 16 + m] = f2b(acc[rb][cb][reg]);
  __syncthreads();

  bf16x8 afr2[2][4];
  #pragma unroll
  for (int rb = 0; rb < 2; ++rb)
    #pragma unroll
    for (int kc = 0; kc < 4; ++kc)
      afr2[rb][kc] = __builtin_bit_cast(bf16x8,
          *(const ushort8*)&w1t[(rl0 + rb * 16 + m) * LDP_ + kc * 32 + quad * 8]);

  f32x4 acc2[2][8];
  #pragma unroll
  for (int rb = 0; rb < 2; ++rb)
    #pragma unroll
    for (int cb = 0; cb < 8; ++cb)
      acc2[rb][cb] = (f32x4){0.f, 0.f, 0.f, 0.f};

  #pragma unroll
  for (int kc = 0; kc < 4; ++kc) {
    #pragma unroll
    for (int cb = 0; cb < 8; ++cb) {
      bf16x8 bfr = __builtin_bit_cast(bf16x8,
          *(const ushort8*)&w2t[(cb * 16 + m) * LDP_ + kc * 32 + quad * 8]);
      acc2[0][cb] = __builtin_amdgcn_mfma_f32_16x16x32_bf16(afr2[0][kc], bfr, acc2[0][cb], 0, 0, 0);
      acc2[1][cb] = __builtin_amdgcn_mfma_f32_16x16x32_bf16(afr2[1][kc], bfr, acc2[1][cb], 0, 0, 0);
    }
  }

  float cs[8];
  #pragma unroll
  for (int cb = 0; cb < 8; ++cb) {
    int col = cb * 16 + m;
    float bb = b2s[col];
    float c = 0.f;
    #pragma unroll
    for (int rb = 0; rb < 2; ++rb)
      #pragma unroll
      for (int reg = 0; reg < 4; ++reg) {
        float v = acc2[rb][cb][reg] + bb;
        if (mode & 1) {
          size_t r = row0 + rb * 16 + quad * 4 + reg;
          hout[r * 128 + col] = f2b(v);
        }
        c += v;
      }
    cs[cb] = c;
  }
  if (mode & 2) {
    #pragma unroll
    for (int cb = 0; cb < 8; ++cb) {
      float s = cs[cb];
      s += __shfl_xor(s, 16);
      s += __shfl_xor(s, 32);                 // sum over quads: this wave's 32 rows
      if (quad == 0) atomicAdd(&sred[cb * 16 + m], s);
    }
    __syncthreads();
    if (tid < 128) atomicAdd(&osum[(size_t)(blockIdx.x >> 1) * 256 + tid], sred[tid]);
  }
}

extern "C" void kernel_launch(void* const* d_in, const int* in_sizes, int n_in,
                              void* d_out, int out_size, void* d_ws, size_t ws_size,
                              hipStream_t stream) {
  const int*   x        = (const int*)d_in[0];
  const int*   ei       = (const int*)d_in[1];
  const int*   los      = (const int*)d_in[2];
  const float* emb      = (const float*)d_in[3];
  const float* lostab   = (const float*)d_in[4];
  const float* g1_w1    = (const float*)d_in[5];
  const float* g1_b1    = (const float*)d_in[6];
  const float* g1_g     = (const float*)d_in[7];
  const float* g1_be    = (const float*)d_in[8];
  const float* g1_w2    = (const float*)d_in[9];
  const float* g1_b2    = (const float*)d_in[10];
  const float* g1_eps   = (const float*)d_in[11];
  const float* g2_w1    = (const float*)d_in[12];
  const float* g2_b1    = (const float*)d_in[13];
  const float* g2_g     = (const float*)d_in[14];
  const float* g2_be    = (const float*)d_in[15];
  const float* g2_w2    = (const float*)d_in[16];
  const float* g2_b2    = (const float*)d_in[17];
  const float* g2_eps   = (const float*)d_in[18];
  const float* g2_ew    = (const float*)d_in[19];
  const float* g2_eb    = (const float*)d_in[20];
  float* out = (float*)d_out;

  char* ws = (char*)d_ws;
  unsigned short* h   = (unsigned short*)(ws);                        // 33,554,432
  unsigned short* z   = (unsigned short*)(ws + (size_t)33554432);     // 33,554,432
  int*   cnt   = (int*)(ws + (size_t)67108864);                       // 524,288
  int*   start = (int*)(ws + (size_t)67633152);                       // 524,288
  int*   cur   = (int*)(ws + (size_t)68157440);                       // 524,288
  int*   bsum  = (int*)(ws + (size_t)68681728);                       // 2,048
  float* cTab  = (float*)(ws + (size_t)68683776);                     // 38,912
  unsigned short* wT = (unsigned short*)(ws + (size_t)68722688);      // 262,144
  int*   lst   = (int*)(ws + (size_t)68984832);                       // 4,194,304

  hipMemsetAsync(cnt, 0, (size_t)N_ * 4, stream);
  hipMemsetAsync(out, 0, (size_t)out_size * 4, stream);

  embed_kernel <<<8192, 256, 0, stream>>>(x, emb, h);
  count_kernel <<<4096, 256, 0, stream>>>(ei, cnt);
  scanA_kernel <<<512, 256, 0, stream>>>(cnt, bsum);
  scanB_kernel <<<1, 512, 0, stream>>>(bsum);
  scanC_kernel <<<512, 256, 0, stream>>>(cnt, bsum, start, cur);
  fill_kernel  <<<4096, 256, 0, stream>>>(ei, cur, lst);
  ctab_kernel  <<<76, 128, 0, stream>>>(lostab, g2_ew, g2_eb, cTab);
  wtrans_kernel<<<512, 256, 0, stream>>>(g1_w1, g1_w2, g2_w1, g2_w2, wT);

  for (int i = 0; i < 2; ++i) {
    agg1_kernel<<<16384, 256, 0, stream>>>(h, z, start, cnt, lst, g1_eps, i);
    mlp_kernel <<<1024, 256, 0, stream>>>(z, h,
        wT + (size_t)i * 16384, wT + (size_t)(2 + i) * 16384,
        g1_b1 + i * 128, g1_g + i * 128, g1_be + i * 128, g1_b2 + i * 128,
        out, i == 1 ? 3 : 1);                 // 2nd mlp also accumulates out[:,0:128]
  }

  for (int i = 0; i < 2; ++i) {
    agg2_kernel<<<16384, 256, 0, stream>>>(h, z, start, cnt, lst, cTab, los, g2_eps, i);
    mlp_kernel <<<1024, 256, 0, stream>>>(z, h,
        wT + (size_t)(4 + i) * 16384, wT + (size_t)(6 + i) * 16384,
        g2_b1 + i * 128, g2_g + i * 128, g2_be + i * 128, g2_b2 + i * 128,
        out + 128, i == 1 ? 2 : 1);           // last mlp: sums only, no h write
  }
}